// Round 1
// baseline (860.883 us; speedup 1.0000x reference)
//
#include <hip/hip_runtime.h>
#include <hip/hip_bf16.h>

#define NUM_AA   20
#define NUM_PAIRS 400   // 20*20
#define DD        64    // embedding dim

// One block per (b, t). Histogram [400][64] fp32 lives in LDS (100 KiB).
// 512 threads = 8 waves; lane (0..63) = d index, wave = position stride.
__global__ __launch_bounds__(512, 1)
void cksaap_kernel(const int* __restrict__ seq,
                   const float* __restrict__ emb,
                   float* __restrict__ out,
                   int B, int L, int k)
{
    __shared__ float hist[NUM_PAIRS * DD];   // 102400 B
    __shared__ int   s_seq[2048];            // 8192 B (L == 2048)

    const int T  = k + 1;
    const int bt = blockIdx.x;
    const int b  = bt / T;
    const int t  = bt % T;
    const int tid = threadIdx.x;

    // zero histogram
    for (int i = tid; i < NUM_PAIRS * DD; i += 512) hist[i] = 0.0f;
    // stage this sequence row
    for (int i = tid; i < L; i += 512) s_seq[i] = seq[(size_t)b * L + i];
    __syncthreads();

    const int lane  = tid & 63;
    const int wave  = tid >> 6;     // 0..7
    const int n     = L - t - 1;
    const float* embb = emb + (size_t)b * L * DD;

    for (int i = wave; i < n; i += 8) {
        const int a = s_seq[i];
        const int c = s_seq[i + t + 1];
        const int idx = a * NUM_AA + c;
        const float v = 0.5f * (embb[(size_t)i * DD + lane] +
                                embb[(size_t)(i + t + 1) * DD + lane]);
        atomicAdd(&hist[idx * DD + lane], v);   // ds_add_f32, lanes hit distinct banks
    }
    __syncthreads();

    const float inv_n = 1.0f / (float)n;
    float* outp = out + (size_t)bt * NUM_PAIRS * DD;
    for (int i = tid; i < NUM_PAIRS * DD; i += 512) {
        outp[i] = hist[i] * inv_n;
    }
}

extern "C" void kernel_launch(void* const* d_in, const int* in_sizes, int n_in,
                              void* d_out, int out_size, void* d_ws, size_t ws_size,
                              hipStream_t stream)
{
    const int*   seq = (const int*)d_in[0];
    const float* emb = (const float*)d_in[1];
    float*       out = (float*)d_out;

    // Shapes per setup_inputs(): seq [B,L], emb [B,L,D]
    const int B = 256;
    const int L = in_sizes[0] / B;            // 2048
    // D = in_sizes[1] / in_sizes[0] == 64
    const int k = out_size / (B * NUM_PAIRS * DD) - 1;   // 3

    const int grid = B * (k + 1);             // 1024 blocks
    cksaap_kernel<<<grid, 512, 0, stream>>>(seq, emb, out, B, L, k);
}